// Round 5
// baseline (6776.598 us; speedup 1.0000x reference)
//
#include <hip/hip_runtime.h>
#include <hip/hip_bf16.h>
#include <math.h>

// Problem constants
#define NN 50000
#define NNP 50048       // rows padded to multiple of BM=128
#define NE 800000
#define DD 256
#define NSTEPS 6

// GEMM tiling
#define BM 128
#define BN 128
#define BK 32

typedef unsigned short u16;
typedef short bf16x8 __attribute__((ext_vector_type(8)));
typedef float f32x4 __attribute__((ext_vector_type(4)));

#define MODE_RELU_P  0   // relu(v+b1) -> planes
#define MODE_PLAIN_F 1   // v+b1 -> fp32
#define MODE_RGATE   2   // T = tanh(aux1 + sig(v+b1+b2)*aux2) -> fp32 (in place over aux1)
#define MODE_ZGATE_F 3   // (1-z)*aux1 + z*x(planes) -> fp32

__device__ __forceinline__ float sigmoidf_(float v) {
    return 1.0f / (1.0f + expf(-v));
}
__device__ __forceinline__ u16 f2bf(float v) {
    union { float f; unsigned u; } x; x.f = v;
    unsigned r = x.u + 0x7FFFu + ((x.u >> 16) & 1u);   // RNE
    return (u16)(r >> 16);
}
__device__ __forceinline__ float bf2f(u16 b) {
    union { unsigned u; float f; } x; x.u = ((unsigned)b) << 16;
    return x.f;
}
__device__ __forceinline__ void split3(float v, u16& h, u16& m, u16& l) {
    h = f2bf(v);
    float r1 = v - bf2f(h);
    m = f2bf(r1);
    float r2 = r1 - bf2f(m);
    l = f2bf(r2);
}
__device__ __forceinline__ unsigned pk(u16 a, u16 b) {
    return (unsigned)a | ((unsigned)b << 16);
}
__device__ __forceinline__ void store_planes(u16* base, size_t ps, size_t off, float v) {
    u16 h, m, l; split3(v, h, m, l);
    base[off] = h; base[ps + off] = m; base[2 * ps + off] = l;
}

// ---------------- CSR build (verified R1/R2/R4) ----------------

__global__ void zero_kernel(int* __restrict__ p, int n) {
    int i = blockIdx.x * blockDim.x + threadIdx.x;
    if (i < n) p[i] = 0;
}
__global__ void hist_kernel(const int* __restrict__ dst, int* __restrict__ counts, int E) {
    int e = blockIdx.x * blockDim.x + threadIdx.x;
    if (e < E) atomicAdd(&counts[dst[e]], 1);
}
__global__ void scan_kernel(const int* __restrict__ counts, int* __restrict__ row_ptr, int n) {
    __shared__ int buf[1024];
    __shared__ int carry;
    const int tid = threadIdx.x;
    if (tid == 0) carry = 0;
    __syncthreads();
    for (int base = 0; base < n; base += 1024) {
        int i = base + tid;
        int v = (i < n) ? counts[i] : 0;
        buf[tid] = v;
        __syncthreads();
        for (int off = 1; off < 1024; off <<= 1) {
            int t = (tid >= off) ? buf[tid - off] : 0;
            __syncthreads();
            buf[tid] += t;
            __syncthreads();
        }
        if (i < n) row_ptr[i] = carry + buf[tid] - v;
        __syncthreads();
        if (tid == 0) carry += buf[1023];
        __syncthreads();
    }
    if (threadIdx.x == 0) row_ptr[n] = carry;
}
__global__ void fill_kernel(const int* __restrict__ src, const int* __restrict__ dst,
                            const int* __restrict__ row_ptr, int* __restrict__ cursor,
                            int* __restrict__ csr_src, int E) {
    int e = blockIdx.x * blockDim.x + threadIdx.x;
    if (e < E) {
        int d = dst[e];
        int p = atomicAdd(&cursor[d], 1);
        csr_src[row_ptr[d] + p] = src[e];
    }
}

// ---------------- fp32 -> 3 bf16 planes (rows padded w/ zero) ----------------
__global__ void split_rows(const float* __restrict__ src, u16* __restrict__ dst,
                           size_t pstride, int srcRows) {
    int row = blockIdx.x;
    int col = threadIdx.x;
    size_t off = (size_t)row * DD + col;
    float v = (row < srcRows) ? src[off] : 0.0f;
    store_planes(dst, pstride, off, v);
}

// ---------------- LDS-free direct-register MFMA GEMM ----------------
// C = epilogue(A @ W^T + bias). A,B as 3 bf16 planes (hi/mid/lo), plane-major.
// KT=512: k>=256 switches to (pA2,pB2). No LDS, no barriers: each wave loads its
// MFMA fragments (16B/lane, 64B row segments) straight from global. A rows are
// wave-private (L1/L2 dedups the 2-wave overlap); B is L2-resident weights.
template <int MODE, int KT>
__global__ __launch_bounds__(256, 3)
void gemm_direct(const u16* __restrict__ pA1, const u16* __restrict__ pA2, size_t psA,
                 const u16* __restrict__ pB1, const u16* __restrict__ pB2, size_t psB,
                 const float* __restrict__ bias1, const float* __restrict__ bias2,
                 const float* __restrict__ aux1, const float* __restrict__ aux2,
                 const u16* __restrict__ auxXp, size_t psX,
                 float* __restrict__ outF, u16* __restrict__ outP, size_t psO, int M) {
    const int tid = threadIdx.x;
    const int lane = tid & 63;
    const int wv = tid >> 6;
    const int wr = wv >> 1;            // wave row 0..1 (64 rows)
    const int wc = wv & 1;             // wave col 0..1 (64 cols)
    const int frow = lane & 15;
    const int kg = lane >> 4;
    const int rowBase = blockIdx.x * BM;
    const int colBase = blockIdx.y * BN;

    // per-lane element offsets into the plane arrays
    const int aoff0 = (rowBase + wr * 64 + frow) * DD + kg * 8;
    const int boff0 = (colBase + wc * 64 + frow) * DD + kg * 8;

    f32x4 acc[4][4] = {};

#pragma unroll 2
    for (int k0 = 0; k0 < KT; k0 += BK) {
        const u16* Ab = (KT == 512 && k0 >= DD) ? pA2 : pA1;
        const u16* Bb = (KT == 512 && k0 >= DD) ? pB2 : pB1;
        const int kc = (KT == 512) ? (k0 & (DD - 1)) : k0;

        bf16x8 af[3][4];
#pragma unroll
        for (int mf = 0; mf < 4; ++mf) {
            const u16* ap = Ab + (size_t)(aoff0 + mf * 16 * DD + kc);
            af[0][mf] = *reinterpret_cast<const bf16x8*>(ap);
            af[1][mf] = *reinterpret_cast<const bf16x8*>(ap + psA);
            af[2][mf] = *reinterpret_cast<const bf16x8*>(ap + 2 * psA);
        }
#pragma unroll
        for (int nf = 0; nf < 4; ++nf) {
            const u16* bp = Bb + (size_t)(boff0 + nf * 16 * DD + kc);
            bf16x8 bh = *reinterpret_cast<const bf16x8*>(bp);
            bf16x8 bm = *reinterpret_cast<const bf16x8*>(bp + psB);
            bf16x8 bl = *reinterpret_cast<const bf16x8*>(bp + 2 * psB);
#pragma unroll
            for (int mf = 0; mf < 4; ++mf) {
                f32x4 c = acc[mf][nf];
                c = __builtin_amdgcn_mfma_f32_16x16x32_bf16(af[0][mf], bh, c, 0, 0, 0);
                c = __builtin_amdgcn_mfma_f32_16x16x32_bf16(af[0][mf], bm, c, 0, 0, 0);
                c = __builtin_amdgcn_mfma_f32_16x16x32_bf16(af[1][mf], bh, c, 0, 0, 0);
                c = __builtin_amdgcn_mfma_f32_16x16x32_bf16(af[0][mf], bl, c, 0, 0, 0);
                c = __builtin_amdgcn_mfma_f32_16x16x32_bf16(af[2][mf], bh, c, 0, 0, 0);
                c = __builtin_amdgcn_mfma_f32_16x16x32_bf16(af[1][mf], bm, c, 0, 0, 0);
                acc[mf][nf] = c;
            }
        }
    }

    // epilogue (identical to R4)
#pragma unroll
    for (int nf = 0; nf < 4; ++nf) {
        int gc = colBase + wc * 64 + nf * 16 + frow;
        float b1v = bias1[gc];
        float b2v = 0.0f;
        if (MODE == MODE_RGATE || MODE == MODE_ZGATE_F) b2v = bias2[gc];
#pragma unroll
        for (int mf = 0; mf < 4; ++mf) {
            f32x4 a = acc[mf][nf];
#pragma unroll
            for (int j = 0; j < 4; ++j) {
                int gr = rowBase + wr * 64 + mf * 16 + kg * 4 + j;
                if (gr < M) {
                    float v = a[j] + b1v + b2v;
                    size_t off = (size_t)gr * DD + gc;
                    if (MODE == MODE_RELU_P) {
                        store_planes(outP, psO, off, fmaxf(v, 0.0f));
                    } else if (MODE == MODE_PLAIN_F) {
                        outF[off] = v;
                    } else if (MODE == MODE_RGATE) {
                        float r = sigmoidf_(v);
                        outF[off] = tanhf(aux1[off] + r * aux2[off]);
                    } else { // MODE_ZGATE_F
                        float z = sigmoidf_(v);
                        float x = bf2f(auxXp[off]) + bf2f(auxXp[psX + off]) +
                                  bf2f(auxXp[2 * psX + off]);
                        outF[off] = (1.0f - z) * aux1[off] + z * x;
                    }
                }
            }
        }
    }
}

// ---------------- segment sum (gather over CSR) -> msg planes ----------------
__global__ __launch_bounds__(256)
void segsum_kernel(const float* __restrict__ h, const int* __restrict__ row_ptr,
                   const int* __restrict__ csr_src, u16* __restrict__ msgP,
                   size_t ps, int n) {
    int node = blockIdx.x * 4 + threadIdx.y;
    if (node >= n) return;
    int d4 = threadIdx.x * 4;
    int s = row_ptr[node];
    int e = row_ptr[node + 1];
    float4 acc = make_float4(0.f, 0.f, 0.f, 0.f);
    for (int j = s; j < e; ++j) {
        int sn = csr_src[j];
        float4 v = *reinterpret_cast<const float4*>(&h[(size_t)sn * DD + d4]);
        acc.x += v.x; acc.y += v.y; acc.z += v.z; acc.w += v.w;
    }
    size_t off = (size_t)node * DD + d4;
    u16 h0,m0,l0,h1,m1,l1,h2,m2,l2,h3,m3,l3;
    split3(acc.x, h0,m0,l0); split3(acc.y, h1,m1,l1);
    split3(acc.z, h2,m2,l2); split3(acc.w, h3,m3,l3);
    *reinterpret_cast<uint2*>(&msgP[off])          = make_uint2(pk(h0,h1), pk(h2,h3));
    *reinterpret_cast<uint2*>(&msgP[ps + off])     = make_uint2(pk(m0,m1), pk(m2,m3));
    *reinterpret_cast<uint2*>(&msgP[2 * ps + off]) = make_uint2(pk(l0,l1), pk(l2,l3));
}

// ---------------- launch ----------------

extern "C" void kernel_launch(void* const* d_in, const int* in_sizes, int n_in,
                              void* d_out, int out_size, void* d_ws, size_t ws_size,
                              hipStream_t stream) {
    const float* x0  = (const float*)d_in[0];
    const float* W1  = (const float*)d_in[1];
    const float* b1  = (const float*)d_in[2];
    const float* W2  = (const float*)d_in[3];
    const float* b2  = (const float*)d_in[4];
    const float* Wih = (const float*)d_in[5];
    const float* bih = (const float*)d_in[6];
    const float* Whh = (const float*)d_in[7];
    const float* bhh = (const float*)d_in[8];
    const int*   src = (const int*)d_in[9];
    const int*   dst = (const int*)d_in[10];

    // workspace layout (~211.9 MB, R4-proven)
    char* ws = (char*)d_ws;
    const size_t PSA = (size_t)NNP * DD;              // elems per activation plane
    const size_t SP  = PSA * 3 * sizeof(u16);         // 76,873,728 B (3 planes)
    const size_t NB  = PSA * sizeof(float);           // 51,249,152 B
    const size_t PSW2 = (size_t)DD * DD;              // 65536
    const size_t PSW3 = (size_t)3 * DD * DD;          // 196608
    u16* XP    = (u16*)(ws);                          // x planes (single buffer)
    u16* TP    = (u16*)(ws + SP);                     // t1 planes, then msg planes
    float* F1  = (float*)(ws + 2 * SP);               // h / Gxn / T fp32
    u16* W1P   = (u16*)(ws + 2 * SP + NB);
    u16* W2P   = W1P + 3 * PSW2;
    u16* WIHP  = W2P + 3 * PSW2;
    u16* WHHP  = WIHP + 3 * PSW3;
    int* counts  = (int*)(WHHP + 3 * PSW3);
    int* cursor  = counts + NN;
    int* row_ptr = cursor + NN;                       // NN+1 ints
    int* csr     = row_ptr + NN + 8;                  // NE ints
    const size_t needed = 2 * SP + NB + 2 * (3 * PSW2 + 3 * PSW3) * sizeof(u16)
                        + (size_t)(2 * NN + NN + 9 + NE) * sizeof(int);
    if (ws_size < needed) return;   // clean fail instead of OOB crash

    float* FOUT = (float*)d_out;    // scratch: Ghn fp32, then x_next fp32 (final = answer)

    // CSR build
    zero_kernel<<<(2 * NN + 255) / 256, 256, 0, stream>>>(counts, 2 * NN);
    hist_kernel<<<(NE + 255) / 256, 256, 0, stream>>>(dst, counts, NE);
    scan_kernel<<<1, 1024, 0, stream>>>(counts, row_ptr, NN);
    fill_kernel<<<(NE + 255) / 256, 256, 0, stream>>>(src, dst, row_ptr, cursor, csr, NE);

    // pre-split weights (once)
    split_rows<<<DD, 256, 0, stream>>>(W1, W1P, PSW2, DD);
    split_rows<<<DD, 256, 0, stream>>>(W2, W2P, PSW2, DD);
    split_rows<<<3 * DD, 256, 0, stream>>>(Wih, WIHP, PSW3, 3 * DD);
    split_rows<<<3 * DD, 256, 0, stream>>>(Whh, WHHP, PSW3, 3 * DD);

    const dim3 grid(NNP / BM, DD / BN);   // 391 x 2

    for (int s = 0; s < NSTEPS; ++s) {
        // x planes for this step (x0 at s=0, else previous step's fp32 x in d_out)
        split_rows<<<NNP, 256, 0, stream>>>((s == 0) ? x0 : FOUT, XP, PSA, NN);

        // t1 = ReLU(x @ W1^T + b1) -> TP planes
        gemm_direct<MODE_RELU_P, 256><<<grid, 256, 0, stream>>>(
            XP, XP, PSA, W1P, W1P, PSW2, b1, nullptr,
            nullptr, nullptr, nullptr, 0, nullptr, TP, PSA, NN);
        // h = t1 @ W2^T + b2 -> F1 fp32
        gemm_direct<MODE_PLAIN_F, 256><<<grid, 256, 0, stream>>>(
            TP, TP, PSA, W2P, W2P, PSW2, b2, nullptr,
            nullptr, nullptr, nullptr, 0, F1, nullptr, 0, NN);
        // msg = segment_sum(h[src], dst) -> TP planes (t1 dead)
        segsum_kernel<<<dim3((NN + 3) / 4), dim3(64, 4), 0, stream>>>(
            F1, row_ptr, csr, TP, PSA, NN);
        // Ghn = x @ Whh_n^T + bhh_n -> FOUT (d_out scratch)
        gemm_direct<MODE_PLAIN_F, 256><<<grid, 256, 0, stream>>>(
            XP, XP, PSA, WHHP + 512 * DD, WHHP + 512 * DD, PSW3, bhh + 512, nullptr,
            nullptr, nullptr, nullptr, 0, FOUT, nullptr, 0, NN);
        // Gxn = msg @ Wih_n^T + bih_n -> F1
        gemm_direct<MODE_PLAIN_F, 256><<<grid, 256, 0, stream>>>(
            TP, TP, PSA, WIHP + 512 * DD, WIHP + 512 * DD, PSW3, bih + 512, nullptr,
            nullptr, nullptr, nullptr, 0, F1, nullptr, 0, NN);
        // T = tanh(Gxn + r*Ghn), r = sig([msg|x]@[Wih_r|Whh_r]^T + bih_r + bhh_r)
        //   -> F1 in place (per-thread read-modify-write of its own element)
        gemm_direct<MODE_RGATE, 512><<<grid, 256, 0, stream>>>(
            TP, XP, PSA, WIHP, WHHP, PSW3, bih, bhh,
            F1, FOUT, nullptr, 0, F1, nullptr, 0, NN);
        // x_next = (1-z)*T + z*x, z = sig([msg|x]@[Wih_z|Whh_z]^T + ...) -> FOUT
        gemm_direct<MODE_ZGATE_F, 512><<<grid, 256, 0, stream>>>(
            TP, XP, PSA, WIHP + 256 * DD, WHHP + 256 * DD, PSW3, bih + 256, bhh + 256,
            F1, nullptr, XP, PSA, FOUT, nullptr, 0, NN);
    }
}

// Round 6
// 3137.128 us; speedup vs baseline: 2.1601x; 2.1601x over previous
//
#include <hip/hip_runtime.h>
#include <hip/hip_bf16.h>
#include <math.h>

// Problem constants
#define NN 50000
#define NNP 50048       // rows padded to multiple of BM=128
#define NE 800000
#define DD 256
#define NSTEPS 6

// GEMM tiling
#define BM 128
#define BN 128
#define BK 32

typedef unsigned short u16;
typedef _Float16 f16x8 __attribute__((ext_vector_type(8)));
typedef float f32x4 __attribute__((ext_vector_type(4)));

#define MODE_RELU_P  0   // relu(v+b1) -> planes
#define MODE_PLAIN_F 1   // v+b1 -> fp32
#define MODE_RGATE   2   // T = tanh(aux1 + sig(v+b1+b2)*aux2) -> fp32 (in place over aux1)
#define MODE_ZGATE_F 3   // (1-z)*aux1 + z*x(planes) -> fp32

__device__ __forceinline__ float sigmoidf_(float v) {
    return 1.0f / (1.0f + expf(-v));
}
__device__ __forceinline__ u16 f2h(float v) {
    _Float16 h = (_Float16)v;            // RNE
    u16 u; __builtin_memcpy(&u, &h, 2); return u;
}
__device__ __forceinline__ float h2f(u16 u) {
    _Float16 h; __builtin_memcpy(&h, &u, 2); return (float)h;
}
// fp16 2-way split: v ~= h + l to 2^-22 relative (residual subtraction exact)
__device__ __forceinline__ void split2(float v, u16& h, u16& l) {
    h = f2h(v);
    float r = v - h2f(h);
    l = f2h(r);
}
__device__ __forceinline__ unsigned pk(u16 a, u16 b) {
    return (unsigned)a | ((unsigned)b << 16);
}
__device__ __forceinline__ void store_planes(u16* base, size_t ps, size_t off, float v) {
    u16 h, l; split2(v, h, l);
    base[off] = h; base[ps + off] = l;
}
__device__ __forceinline__ void gload16(const void* g, void* l) {
    __builtin_amdgcn_global_load_lds(
        (const __attribute__((address_space(1))) void*)g,
        (__attribute__((address_space(3))) void*)l, 16, 0, 0);
}

// ---------------- CSR build (verified R1/R2/R4) ----------------

__global__ void zero_kernel(int* __restrict__ p, int n) {
    int i = blockIdx.x * blockDim.x + threadIdx.x;
    if (i < n) p[i] = 0;
}
__global__ void hist_kernel(const int* __restrict__ dst, int* __restrict__ counts, int E) {
    int e = blockIdx.x * blockDim.x + threadIdx.x;
    if (e < E) atomicAdd(&counts[dst[e]], 1);
}
__global__ void scan_kernel(const int* __restrict__ counts, int* __restrict__ row_ptr, int n) {
    __shared__ int buf[1024];
    __shared__ int carry;
    const int tid = threadIdx.x;
    if (tid == 0) carry = 0;
    __syncthreads();
    for (int base = 0; base < n; base += 1024) {
        int i = base + tid;
        int v = (i < n) ? counts[i] : 0;
        buf[tid] = v;
        __syncthreads();
        for (int off = 1; off < 1024; off <<= 1) {
            int t = (tid >= off) ? buf[tid - off] : 0;
            __syncthreads();
            buf[tid] += t;
            __syncthreads();
        }
        if (i < n) row_ptr[i] = carry + buf[tid] - v;
        __syncthreads();
        if (tid == 0) carry += buf[1023];
        __syncthreads();
    }
    if (threadIdx.x == 0) row_ptr[n] = carry;
}
__global__ void fill_kernel(const int* __restrict__ src, const int* __restrict__ dst,
                            const int* __restrict__ row_ptr, int* __restrict__ cursor,
                            int* __restrict__ csr_src, int E) {
    int e = blockIdx.x * blockDim.x + threadIdx.x;
    if (e < E) {
        int d = dst[e];
        int p = atomicAdd(&cursor[d], 1);
        csr_src[row_ptr[d] + p] = src[e];
    }
}

// ---------------- fp32 -> 2 fp16 planes (rows padded w/ zero) ----------------
__global__ void split_rows(const float* __restrict__ src, u16* __restrict__ dst,
                           size_t pstride, int srcRows) {
    int row = blockIdx.x;
    int col = threadIdx.x;
    size_t off = (size_t)row * DD + col;
    float v = (row < srcRows) ? src[off] : 0.0f;
    store_planes(dst, pstride, off, v);
}

// ---------------- split-plane fp16 MFMA GEMM (R4 structure, 2 planes) ----------------
// C = epilogue(A @ W^T + bias). A,B as 2 fp16 planes (hi/lo), plane-major.
// Dual-K (K=512): k<256 from (pA1,pB1), k>=256 from (pA2,pB2).
// 3-term product (hh, hl, lh) == fp32-grade (2^-22) precision.
// LDS staged via global_load_lds; source chunk-XOR swizzle keeps ds_read_b128
// fragment reads <=2-way bank conflicted (R4-verified: 0 conflicts).
template <int MODE>
__global__ __launch_bounds__(256, 4)
void gemm_planes(const u16* __restrict__ pA1, const u16* __restrict__ pA2, size_t psA,
                 const u16* __restrict__ pB1, const u16* __restrict__ pB2, size_t psB,
                 const float* __restrict__ bias1, const float* __restrict__ bias2,
                 const float* __restrict__ aux1, const float* __restrict__ aux2,
                 const u16* __restrict__ auxXp, size_t psX,
                 float* __restrict__ outF, u16* __restrict__ outP, size_t psO,
                 int M, int K) {
    __shared__ u16 lds[16384];   // A: 2 planes x [128][32] = 8192; B same at +8192

    const int tid = threadIdx.x;
    const int lane = tid & 63;
    const int wv = tid >> 6;
    const int wr = wv >> 1;            // wave row 0..1 (64 rows)
    const int wc = wv & 1;             // wave col 0..1 (64 cols)
    const int frow = lane & 15;
    const int kg = lane >> 4;
    const int rowBase = blockIdx.x * BM;
    const int colBase = blockIdx.y * BN;

    // staging plan: 32 x 1KB wave-issues per block, 8 per wave.
    // q = wv*8+j; q<16: A plane (q>>3), sub-tile q&7; q>=16: B plane ((q-16)>>3).
    int offj[8]; int ldsoffj[8]; bool isBj[8];
#pragma unroll
    for (int j = 0; j < 8; ++j) {
        int q = wv * 8 + j;
        bool isB = q >= 16;
        int p = (q >> 3) & 1;
        int sub = q & 7;
        int row = sub * 16 + (lane >> 2);
        int chunk = (lane & 3) ^ ((row >> 1) & 3);
        int ps = isB ? (int)psB : (int)psA;
        int grow = (isB ? colBase : rowBase) + row;
        offj[j] = p * ps + grow * DD + chunk * 8;
        ldsoffj[j] = q * 512;
        isBj[j] = isB;
    }

    f32x4 acc[4][4] = {};

    for (int k0 = 0; k0 < K; k0 += BK) {
        const u16* Ab; const u16* Bb; int kc;
        if (k0 < DD) { Ab = pA1; Bb = pB1; kc = k0; }
        else         { Ab = pA2; Bb = pB2; kc = k0 - DD; }

#pragma unroll
        for (int j = 0; j < 8; ++j) {
            const u16* gp = (isBj[j] ? Bb : Ab) + offj[j] + kc;
            gload16(gp, &lds[ldsoffj[j]]);
        }
        __syncthreads();

        f16x8 af[2][4];
#pragma unroll
        for (int mf = 0; mf < 4; ++mf) {
            int row = wr * 64 + mf * 16 + frow;
            int off = row * 32 + ((kg ^ ((row >> 1) & 3)) * 8);
            af[0][mf] = *reinterpret_cast<const f16x8*>(&lds[off]);
            af[1][mf] = *reinterpret_cast<const f16x8*>(&lds[4096 + off]);
        }
#pragma unroll
        for (int nf = 0; nf < 4; ++nf) {
            int brow = wc * 64 + nf * 16 + frow;
            int boff = 8192 + brow * 32 + ((kg ^ ((brow >> 1) & 3)) * 8);
            f16x8 bh = *reinterpret_cast<const f16x8*>(&lds[boff]);
            f16x8 bl = *reinterpret_cast<const f16x8*>(&lds[boff + 4096]);
#pragma unroll
            for (int mf = 0; mf < 4; ++mf) {
                f32x4 c = acc[mf][nf];
                c = __builtin_amdgcn_mfma_f32_16x16x32_f16(af[0][mf], bh, c, 0, 0, 0);
                c = __builtin_amdgcn_mfma_f32_16x16x32_f16(af[0][mf], bl, c, 0, 0, 0);
                c = __builtin_amdgcn_mfma_f32_16x16x32_f16(af[1][mf], bh, c, 0, 0, 0);
                acc[mf][nf] = c;
            }
        }
        __syncthreads();
    }

    // epilogue (R4-identical layout)
#pragma unroll
    for (int nf = 0; nf < 4; ++nf) {
        int gc = colBase + wc * 64 + nf * 16 + frow;
        float b1v = bias1[gc];
        float b2v = 0.0f;
        if (MODE == MODE_RGATE || MODE == MODE_ZGATE_F) b2v = bias2[gc];
#pragma unroll
        for (int mf = 0; mf < 4; ++mf) {
            f32x4 a = acc[mf][nf];
#pragma unroll
            for (int j = 0; j < 4; ++j) {
                int gr = rowBase + wr * 64 + mf * 16 + kg * 4 + j;
                if (gr < M) {
                    float v = a[j] + b1v + b2v;
                    size_t off = (size_t)gr * DD + gc;
                    if (MODE == MODE_RELU_P) {
                        store_planes(outP, psO, off, fmaxf(v, 0.0f));
                    } else if (MODE == MODE_PLAIN_F) {
                        outF[off] = v;
                    } else if (MODE == MODE_RGATE) {
                        float r = sigmoidf_(v);
                        outF[off] = tanhf(aux1[off] + r * aux2[off]);
                    } else { // MODE_ZGATE_F
                        float z = sigmoidf_(v);
                        float x = h2f(auxXp[off]) + h2f(auxXp[psX + off]);
                        outF[off] = (1.0f - z) * aux1[off] + z * x;
                    }
                }
            }
        }
    }
}

// ---------------- segment sum (gather over CSR) -> msg planes ----------------
__global__ __launch_bounds__(256)
void segsum_kernel(const float* __restrict__ h, const int* __restrict__ row_ptr,
                   const int* __restrict__ csr_src, u16* __restrict__ msgP,
                   size_t ps, int n) {
    int node = blockIdx.x * 4 + threadIdx.y;
    if (node >= n) return;
    int d4 = threadIdx.x * 4;
    int s = row_ptr[node];
    int e = row_ptr[node + 1];
    float4 acc = make_float4(0.f, 0.f, 0.f, 0.f);
    for (int j = s; j < e; ++j) {
        int sn = csr_src[j];
        float4 v = *reinterpret_cast<const float4*>(&h[(size_t)sn * DD + d4]);
        acc.x += v.x; acc.y += v.y; acc.z += v.z; acc.w += v.w;
    }
    size_t off = (size_t)node * DD + d4;
    u16 h0,l0,h1,l1,h2,l2,h3,l3;
    split2(acc.x, h0,l0); split2(acc.y, h1,l1);
    split2(acc.z, h2,l2); split2(acc.w, h3,l3);
    *reinterpret_cast<uint2*>(&msgP[off])      = make_uint2(pk(h0,h1), pk(h2,h3));
    *reinterpret_cast<uint2*>(&msgP[ps + off]) = make_uint2(pk(l0,l1), pk(l2,l3));
}

// ---------------- launch ----------------

extern "C" void kernel_launch(void* const* d_in, const int* in_sizes, int n_in,
                              void* d_out, int out_size, void* d_ws, size_t ws_size,
                              hipStream_t stream) {
    const float* x0  = (const float*)d_in[0];
    const float* W1  = (const float*)d_in[1];
    const float* b1  = (const float*)d_in[2];
    const float* W2  = (const float*)d_in[3];
    const float* b2  = (const float*)d_in[4];
    const float* Wih = (const float*)d_in[5];
    const float* bih = (const float*)d_in[6];
    const float* Whh = (const float*)d_in[7];
    const float* bhh = (const float*)d_in[8];
    const int*   src = (const int*)d_in[9];
    const int*   dst = (const int*)d_in[10];

    // workspace layout (~160 MB)
    char* ws = (char*)d_ws;
    const size_t PSA = (size_t)NNP * DD;              // elems per activation plane
    const size_t SP  = PSA * 2 * sizeof(u16);         // 51.25 MB (2 fp16 planes)
    const size_t NB  = PSA * sizeof(float);           // 51.25 MB
    const size_t PSW2 = (size_t)DD * DD;              // 65536
    const size_t PSW3 = (size_t)3 * DD * DD;          // 196608
    u16* XP    = (u16*)(ws);                          // x planes (single buffer)
    u16* TP    = (u16*)(ws + SP);                     // t1 planes, then msg planes
    float* F1  = (float*)(ws + 2 * SP);               // h / Gxn / T fp32
    u16* W1P   = (u16*)(ws + 2 * SP + NB);
    u16* W2P   = W1P + 2 * PSW2;
    u16* WIHP  = W2P + 2 * PSW2;
    u16* WHHP  = WIHP + 2 * PSW3;
    int* counts  = (int*)(WHHP + 2 * PSW3);
    int* cursor  = counts + NN;
    int* row_ptr = cursor + NN;                       // NN+1 ints
    int* csr     = row_ptr + NN + 8;                  // NE ints
    const size_t needed = 2 * SP + NB + 2 * (2 * PSW2 + 2 * PSW3) * sizeof(u16)
                        + (size_t)(2 * NN + NN + 9 + NE) * sizeof(int);
    if (ws_size < needed) return;   // clean fail instead of OOB crash

    float* FOUT = (float*)d_out;    // scratch: Ghn fp32, then x_next fp32 (final = answer)

    // CSR build
    zero_kernel<<<(2 * NN + 255) / 256, 256, 0, stream>>>(counts, 2 * NN);
    hist_kernel<<<(NE + 255) / 256, 256, 0, stream>>>(dst, counts, NE);
    scan_kernel<<<1, 1024, 0, stream>>>(counts, row_ptr, NN);
    fill_kernel<<<(NE + 255) / 256, 256, 0, stream>>>(src, dst, row_ptr, cursor, csr, NE);

    // pre-split weights (once)
    split_rows<<<DD, 256, 0, stream>>>(W1, W1P, PSW2, DD);
    split_rows<<<DD, 256, 0, stream>>>(W2, W2P, PSW2, DD);
    split_rows<<<3 * DD, 256, 0, stream>>>(Wih, WIHP, PSW3, 3 * DD);
    split_rows<<<3 * DD, 256, 0, stream>>>(Whh, WHHP, PSW3, 3 * DD);

    const dim3 grid(NNP / BM, DD / BN);   // 391 x 2

    for (int s = 0; s < NSTEPS; ++s) {
        // x planes for this step (x0 at s=0, else previous step's fp32 x in d_out)
        split_rows<<<NNP, 256, 0, stream>>>((s == 0) ? x0 : FOUT, XP, PSA, NN);

        // t1 = ReLU(x @ W1^T + b1) -> TP planes
        gemm_planes<MODE_RELU_P><<<grid, 256, 0, stream>>>(
            XP, XP, PSA, W1P, W1P, PSW2, b1, nullptr,
            nullptr, nullptr, nullptr, 0, nullptr, TP, PSA, NN, 256);
        // h = t1 @ W2^T + b2 -> F1 fp32
        gemm_planes<MODE_PLAIN_F><<<grid, 256, 0, stream>>>(
            TP, TP, PSA, W2P, W2P, PSW2, b2, nullptr,
            nullptr, nullptr, nullptr, 0, F1, nullptr, 0, NN, 256);
        // msg = segment_sum(h[src], dst) -> TP planes (t1 dead)
        segsum_kernel<<<dim3((NN + 3) / 4), dim3(64, 4), 0, stream>>>(
            F1, row_ptr, csr, TP, PSA, NN);
        // Ghn = x @ Whh_n^T + bhh_n -> FOUT (d_out scratch; h in F1 dead after segsum)
        gemm_planes<MODE_PLAIN_F><<<grid, 256, 0, stream>>>(
            XP, XP, PSA, WHHP + 512 * DD, WHHP + 512 * DD, PSW3, bhh + 512, nullptr,
            nullptr, nullptr, nullptr, 0, FOUT, nullptr, 0, NN, 256);
        // Gxn = msg @ Wih_n^T + bih_n -> F1
        gemm_planes<MODE_PLAIN_F><<<grid, 256, 0, stream>>>(
            TP, TP, PSA, WIHP + 512 * DD, WIHP + 512 * DD, PSW3, bih + 512, nullptr,
            nullptr, nullptr, nullptr, 0, F1, nullptr, 0, NN, 256);
        // T = tanh(Gxn + r*Ghn), r = sig([msg|x]@[Wih_r|Whh_r]^T + bih_r + bhh_r)
        //   -> F1 in place (per-thread read-modify-write of its own element)
        gemm_planes<MODE_RGATE><<<grid, 256, 0, stream>>>(
            TP, XP, PSA, WIHP, WHHP, PSW3, bih, bhh,
            F1, FOUT, nullptr, 0, F1, nullptr, 0, NN, 512);
        // x_next = (1-z)*T + z*x, z = sig([msg|x]@[Wih_z|Whh_z]^T + ...) -> FOUT
        gemm_planes<MODE_ZGATE_F><<<grid, 256, 0, stream>>>(
            TP, XP, PSA, WIHP + 256 * DD, WHHP + 256 * DD, PSW3, bih + 256, bhh + 256,
            F1, nullptr, XP, PSA, FOUT, nullptr, 0, NN, 512);
    }
}